// Round 1
// 2617.784 us; speedup vs baseline: 1.2682x; 1.2682x over previous
//
#include <hip/hip_runtime.h>
#include <hip/hip_bf16.h>
#include <cstdint>
#include <cstddef>

#define TOKENS 8192
#define HIDDEN 4096
#define FFN    16384
#define EPS    1e-5f

typedef __attribute__((ext_vector_type(4))) float  floatx4;
typedef __attribute__((ext_vector_type(8))) short  shortx8;

__device__ __forceinline__ short f2bf(float f) {
  __hip_bfloat16 h = __float2bfloat16(f);
  return *reinterpret_cast<short*>(&h);
}

// async global->LDS, 16 bytes per lane. LDS dest is wave-uniform base;
// HW scatters lane i to base + i*16.
__device__ __forceinline__ void async_load16(const void* g, void* l) {
  __builtin_amdgcn_global_load_lds(
      (__attribute__((address_space(1))) void*)(uintptr_t)g,
      (__attribute__((address_space(3))) void*)l,
      16, 0, 0);
}

// ---------------- LayerNorm: fp32 [row, HIDDEN] -> bf16 ----------------
__global__ __launch_bounds__(256) void ln_kernel(
    const float* __restrict__ x, const float* __restrict__ gamma,
    const float* __restrict__ beta, short* __restrict__ out) {
  const int row  = blockIdx.x;
  const int tid  = threadIdx.x;
  const int wave = tid >> 6, lane = tid & 63;
  const float4* xr = (const float4*)(x + (size_t)row * HIDDEN);
  float4 v[4];
  float sum = 0.f, sq = 0.f;
#pragma unroll
  for (int i = 0; i < 4; ++i) {
    v[i] = xr[tid + i * 256];
    sum += v[i].x + v[i].y + v[i].z + v[i].w;
    sq  += v[i].x * v[i].x + v[i].y * v[i].y + v[i].z * v[i].z + v[i].w * v[i].w;
  }
#pragma unroll
  for (int o = 32; o > 0; o >>= 1) {
    sum += __shfl_xor(sum, o);
    sq  += __shfl_xor(sq, o);
  }
  __shared__ float s_sum[4], s_sq[4];
  if (lane == 0) { s_sum[wave] = sum; s_sq[wave] = sq; }
  __syncthreads();
  const float ts = s_sum[0] + s_sum[1] + s_sum[2] + s_sum[3];
  const float tq = s_sq[0] + s_sq[1] + s_sq[2] + s_sq[3];
  const float mu  = ts * (1.f / HIDDEN);
  const float var = tq * (1.f / HIDDEN) - mu * mu;
  const float rs  = rsqrtf(var + EPS);
  short4* orow = (short4*)(out + (size_t)row * HIDDEN);
#pragma unroll
  for (int i = 0; i < 4; ++i) {
    float4 g = ((const float4*)gamma)[tid + i * 256];
    float4 b = ((const float4*)beta)[tid + i * 256];
    short4 o;
    o.x = f2bf((v[i].x - mu) * rs * g.x + b.x);
    o.y = f2bf((v[i].y - mu) * rs * g.y + b.y);
    o.z = f2bf((v[i].z - mu) * rs * g.z + b.z);
    o.w = f2bf((v[i].w - mu) * rs * g.w + b.w);
    orow[tid + i * 256] = o;
  }
}

// ---------- transpose + fp32->bf16: in [R,C] f32 -> out [C,R] bf16 ----------
__global__ __launch_bounds__(256) void transpose_bf16(
    const float* __restrict__ in, short* __restrict__ out, int R, int C) {
  __shared__ float tile[32][33];
  const int c0 = blockIdx.x * 32, r0 = blockIdx.y * 32;
  const int tx = threadIdx.x, ty = threadIdx.y;  // block (32,8)
#pragma unroll
  for (int i = 0; i < 32; i += 8)
    tile[ty + i][tx] = in[(size_t)(r0 + ty + i) * C + c0 + tx];
  __syncthreads();
#pragma unroll
  for (int i = 0; i < 32; i += 8)
    out[(size_t)(c0 + ty + i) * R + r0 + tx] = f2bf(tile[tx][ty + i]);
}

// =====================================================================
// bf16 GEMM, B^T layout — 256x256 tile, BK=64, 8-phase schedule
// (T1 XCD swizzle + T2 LDS XOR swizzle + T3/T4 counted vmcnt + T5 setprio)
// 512 threads = 8 waves (2M x 4N); per-wave output 128x64, fragments
// interleaved at 16-granularity: rows wr*16 + i*32, cols wc*16 + j*64,
// so i<4 -> A-half0, i>=4 -> A-half1; j<2 -> B-half0, j>=2 -> B-half1.
// LDS: 2 dbuf x (A:2 halves + B:2 halves) x [128][64] bf16 = 128 KiB.
// Swizzle: 16B-slot index ^= (row&7); global source pre-inverse-swizzled
// so global_load_lds dest stays linear (rule 21).
// =====================================================================
#define BM 256
#define BN 256
#define BK 64

__device__ __forceinline__ shortx8 frag_ld(const short* half, int rowbase,
                                           int kk, int lane) {
  const int row  = rowbase + (lane & 15);
  const int slot = (kk << 2) + (lane >> 4);         // 16B slot 0..7
  return *(const shortx8*)&half[row * BK + ((slot ^ (row & 7)) << 3)];
}

__device__ __forceinline__ void ds_a(shortx8 (&f)[4][2], const short* half,
                                     int rb, int lane) {
#pragma unroll
  for (int ii = 0; ii < 4; ++ii)
#pragma unroll
    for (int kk = 0; kk < 2; ++kk)
      f[ii][kk] = frag_ld(half, rb + ii * 32, kk, lane);
}

__device__ __forceinline__ void ds_b(shortx8 (&f)[2][2], const short* half,
                                     int rb, int lane) {
#pragma unroll
  for (int jj = 0; jj < 2; ++jj)
#pragma unroll
    for (int kk = 0; kk < 2; ++kk)
      f[jj][kk] = frag_ld(half, rb + jj * 64, kk, lane);
}

template <int IH, int JH>
__device__ __forceinline__ void mmq(floatx4 (&acc)[8][4],
                                    const shortx8 (&aF)[4][2],
                                    const shortx8 (&bF)[2][2]) {
#pragma unroll
  for (int ii = 0; ii < 4; ++ii)
#pragma unroll
    for (int jj = 0; jj < 2; ++jj) {
      floatx4 c = acc[IH * 4 + ii][JH * 2 + jj];
      c = __builtin_amdgcn_mfma_f32_16x16x32_bf16(aF[ii][0], bF[jj][0], c, 0, 0, 0);
      c = __builtin_amdgcn_mfma_f32_16x16x32_bf16(aF[ii][1], bF[jj][1], c, 0, 0, 0);
      acc[IH * 4 + ii][JH * 2 + jj] = c;
    }
}

// Stage one 128x64 half-tile: 16 chunks of 64 rows->8 rows... each chunk is
// 8 rows (1024 B); wave issues 2 chunks. Global column slot pre-XORed with
// row&7 so linear LDS dest + swizzled frag_ld form the same involution.
__device__ __forceinline__ void stage_half(const short* G, int K, int k0,
                                           short* lhalf, int wave, int lane) {
  const int r = lane >> 3;                        // row within chunk, 0..7
  const int c = ((lane & 7) ^ r) << 3;            // inverse-swizzled col
#pragma unroll
  for (int n = 0; n < 2; ++n) {
    const int chunk = wave * 2 + n;               // 0..15
    async_load16(G + (size_t)(chunk * 8 + r) * K + k0 + c,
                 lhalf + chunk * 512);            // 512 shorts = 1024 B
  }
}

#define BARRIER() asm volatile("s_barrier" ::: "memory")
#define VMCNT(N)  asm volatile("s_waitcnt vmcnt(" #N ")" ::: "memory")

template <bool GELU>
__global__ __launch_bounds__(512, 2) void gemm_bt(
    const short* __restrict__ A,   // [M,K] bf16
    const short* __restrict__ Bt,  // [N,K] bf16
    const float* __restrict__ bias,
    void* __restrict__ Cptr, int M, int N, int K) {
  __shared__ __align__(16) short lds[65536];  // 128 KiB
  short* sA = lds;                            // [2][2][8192]
  short* sB = lds + 32768;

  const int tid  = threadIdx.x;
  const int wave = tid >> 6, lane = tid & 63;
  const int wr16 = (wave >> 2) * 16;   // M sub-offset
  const int wc16 = (wave & 3) * 16;    // N sub-offset

  // T1: XCD-aware bijective swizzle (nwg % 8 == 0 for both GEMMs here)
  const int nwg  = gridDim.x * gridDim.y;
  const int orig = blockIdx.y * gridDim.x + blockIdx.x;
  const int swz  = (orig & 7) * (nwg >> 3) + (orig >> 3);
  const int m0 = (swz / gridDim.x) * BM;
  const int n0 = (swz % gridDim.x) * BN;

  const short* Ab    = A  + (size_t)m0 * K;
  const short* Bb    = Bt + (size_t)n0 * K;
  const short* Ab128 = Ab + (size_t)128 * K;
  const short* Bb128 = Bb + (size_t)128 * K;

  floatx4 acc[8][4] = {};
  shortx8 aF[4][2], bF[2][2];

  const int NT = K / BK;

  // Prologue: stage tile 0 halves in consumption order A0,B0,A1,B1 (8 loads).
  // vmcnt(4) certifies A0,B0; A1,B1 (4 loads) stay in flight.
  stage_half(Ab,    K, 0, sA,        wave, lane);
  stage_half(Bb,    K, 0, sB,        wave, lane);
  stage_half(Ab128, K, 0, sA + 8192, wave, lane);
  stage_half(Bb128, K, 0, sB + 8192, wave, lane);
  VMCNT(4);
  BARRIER();

  // Steady-state ledger (per wave, 2 loads per stage), staging order per
  // tile: P1->A0', P2->B0', P3->A1', P4->B1'.
  //   end-P1: out={A1,B1,A0'}=6, need A1  -> vmcnt(4)
  //   end-P2: out={B1,A0',B0'}=6, need B1 -> vmcnt(4)
  //   end-P3: out=6, nothing needed       -> no wait
  //   end-P4: out=8, need A0',B0'         -> vmcnt(4)
  for (int t = 0; t < NT - 1; ++t) {
    const int d = t & 1;
    const short* pA = sA + d * 16384;
    const short* pB = sB + d * 16384;
    short* qA = sA + (d ^ 1) * 16384;
    short* qB = sB + (d ^ 1) * 16384;
    const int kn = (t + 1) * BK;

    // P1: read A0,B0 ; stage A0' ; MFMA (ihalf0 x jhalf0)
    ds_a(aF, pA, wr16, lane);
    ds_b(bF, pB, wc16, lane);
    stage_half(Ab, K, kn, qA, wave, lane);
    BARRIER();
    __builtin_amdgcn_sched_barrier(0);
    __builtin_amdgcn_s_setprio(1);
    mmq<0, 0>(acc, aF, bF);
    __builtin_amdgcn_s_setprio(0);
    VMCNT(4);
    BARRIER();

    // P2: read A1 (keep B0 frags) ; stage B0' ; MFMA (1,0)
    ds_a(aF, pA + 8192, wr16, lane);
    stage_half(Bb, K, kn, qB, wave, lane);
    BARRIER();
    __builtin_amdgcn_sched_barrier(0);
    __builtin_amdgcn_s_setprio(1);
    mmq<1, 0>(acc, aF, bF);
    __builtin_amdgcn_s_setprio(0);
    VMCNT(4);
    BARRIER();

    // P3: read B1 (keep A1 frags) ; stage A1' ; MFMA (1,1)
    ds_b(bF, pB + 8192, wc16, lane);
    stage_half(Ab128, K, kn, qA + 8192, wave, lane);
    BARRIER();
    __builtin_amdgcn_sched_barrier(0);
    __builtin_amdgcn_s_setprio(1);
    mmq<1, 1>(acc, aF, bF);
    __builtin_amdgcn_s_setprio(0);
    BARRIER();

    // P4: re-read A0 (keep B1 frags) ; stage B1' ; MFMA (0,1)
    ds_a(aF, pA, wr16, lane);
    stage_half(Bb128, K, kn, qB + 8192, wave, lane);
    BARRIER();
    __builtin_amdgcn_sched_barrier(0);
    __builtin_amdgcn_s_setprio(1);
    mmq<0, 1>(acc, aF, bF);
    __builtin_amdgcn_s_setprio(0);
    VMCNT(4);
    BARRIER();
  }

  // Last tile: no staging; tighter waits (A1,B1 still in flight at entry).
  {
    const int d = (NT - 1) & 1;
    const short* pA = sA + d * 16384;
    const short* pB = sB + d * 16384;

    ds_a(aF, pA, wr16, lane);
    ds_b(bF, pB, wc16, lane);
    BARRIER();
    __builtin_amdgcn_sched_barrier(0);
    __builtin_amdgcn_s_setprio(1);
    mmq<0, 0>(acc, aF, bF);
    __builtin_amdgcn_s_setprio(0);
    VMCNT(2);            // certify A1
    BARRIER();

    ds_a(aF, pA + 8192, wr16, lane);
    BARRIER();
    __builtin_amdgcn_sched_barrier(0);
    __builtin_amdgcn_s_setprio(1);
    mmq<1, 0>(acc, aF, bF);
    __builtin_amdgcn_s_setprio(0);
    VMCNT(0);            // certify B1 (final drain — epilogue only)
    BARRIER();

    ds_b(bF, pB + 8192, wc16, lane);
    BARRIER();
    __builtin_amdgcn_sched_barrier(0);
    __builtin_amdgcn_s_setprio(1);
    mmq<1, 1>(acc, aF, bF);
    __builtin_amdgcn_s_setprio(0);
    BARRIER();

    ds_a(aF, pA, wr16, lane);
    __builtin_amdgcn_s_setprio(1);
    mmq<0, 1>(acc, aF, bF);
    __builtin_amdgcn_s_setprio(0);
  }

  // Epilogue: C/D layout col=lane&15, row=(lane>>4)*4+reg.
  const int quad = lane >> 4;
  const int cl   = lane & 15;
  float bv[4];
#pragma unroll
  for (int j = 0; j < 4; ++j) bv[j] = bias[n0 + wc16 + j * 64 + cl];
#pragma unroll
  for (int i = 0; i < 8; ++i) {
    const int gr = m0 + wr16 + i * 32 + quad * 4;
#pragma unroll
    for (int j = 0; j < 4; ++j) {
      const int gc = n0 + wc16 + j * 64 + cl;
#pragma unroll
      for (int r = 0; r < 4; ++r) {
        float v = acc[i][j][r] + bv[j];
        if constexpr (GELU) {
          v = 0.5f * v * (1.0f + erff(v * 0.70710678118654752f));
          ((short*)Cptr)[(size_t)(gr + r) * N + gc] = f2bf(v);
        } else {
          ((float*)Cptr)[(size_t)(gr + r) * N + gc] = v;
        }
      }
    }
  }
}

extern "C" void kernel_launch(void* const* d_in, const int* in_sizes, int n_in,
                              void* d_out, int out_size, void* d_ws, size_t ws_size,
                              hipStream_t stream) {
  const float* x     = (const float*)d_in[0];
  const float* gamma = (const float*)d_in[1];
  const float* beta  = (const float*)d_in[2];
  const float* fc1   = (const float*)d_in[3];  // [HIDDEN, FFN]
  const float* b1    = (const float*)d_in[4];  // [FFN]
  const float* fc2   = (const float*)d_in[5];  // [FFN, HIDDEN]
  const float* b2    = (const float*)d_in[6];  // [HIDDEN]
  float* out = (float*)d_out;

  // ws layout (peak 448 MiB):
  //   [0,128Mi)   fc1_bt [FFN,HIDDEN] bf16  -> later reused for fc2_bt
  //   [128,384Mi) h      [TOKENS,FFN] bf16
  //   [384,448Mi) ln     [TOKENS,HIDDEN] bf16
  char* ws = (char*)d_ws;
  const size_t MiB = 1024 * 1024;
  short* fc1_bt = (short*)(ws);
  short* h      = (short*)(ws + 128 * MiB);
  short* ln     = (short*)(ws + 384 * MiB);
  short* fc2_bt = (short*)(ws);  // overwrites fc1_bt after GEMM1 (stream-ordered)

  transpose_bf16<<<dim3(FFN / 32, HIDDEN / 32), dim3(32, 8), 0, stream>>>(
      fc1, fc1_bt, HIDDEN, FFN);
  ln_kernel<<<dim3(TOKENS), dim3(256), 0, stream>>>(x, gamma, beta, ln);
  gemm_bt<true><<<dim3(FFN / BN, TOKENS / BM), dim3(512), 0, stream>>>(
      ln, fc1_bt, b1, h, TOKENS, FFN, HIDDEN);
  transpose_bf16<<<dim3(HIDDEN / 32, FFN / 32), dim3(32, 8), 0, stream>>>(
      fc2, fc2_bt, FFN, HIDDEN);
  gemm_bt<false><<<dim3(HIDDEN / BN, TOKENS / BM), dim3(512), 0, stream>>>(
      h, fc2_bt, b2, out, TOKENS, HIDDEN, FFN);
}

// Round 2
// 2475.739 us; speedup vs baseline: 1.3410x; 1.0574x over previous
//
#include <hip/hip_runtime.h>
#include <hip/hip_bf16.h>
#include <cstdint>
#include <cstddef>

#define TOKENS 8192
#define HIDDEN 4096
#define FFN    16384
#define EPS    1e-5f

typedef __attribute__((ext_vector_type(4))) float  floatx4;
typedef __attribute__((ext_vector_type(8))) short  shortx8;

__device__ __forceinline__ short f2bf(float f) {
  __hip_bfloat16 h = __float2bfloat16(f);
  return *reinterpret_cast<short*>(&h);
}

// async global->LDS, 16 bytes per lane. LDS dest is wave-uniform base;
// HW scatters lane i to base + i*16.
__device__ __forceinline__ void async_load16(const void* g, void* l) {
  __builtin_amdgcn_global_load_lds(
      (__attribute__((address_space(1))) void*)(uintptr_t)g,
      (__attribute__((address_space(3))) void*)l,
      16, 0, 0);
}

// ---------------- LayerNorm: fp32 [row, HIDDEN] -> bf16 ----------------
__global__ __launch_bounds__(256) void ln_kernel(
    const float* __restrict__ x, const float* __restrict__ gamma,
    const float* __restrict__ beta, short* __restrict__ out) {
  const int row  = blockIdx.x;
  const int tid  = threadIdx.x;
  const int wave = tid >> 6, lane = tid & 63;
  const float4* xr = (const float4*)(x + (size_t)row * HIDDEN);
  float4 v[4];
  float sum = 0.f, sq = 0.f;
#pragma unroll
  for (int i = 0; i < 4; ++i) {
    v[i] = xr[tid + i * 256];
    sum += v[i].x + v[i].y + v[i].z + v[i].w;
    sq  += v[i].x * v[i].x + v[i].y * v[i].y + v[i].z * v[i].z + v[i].w * v[i].w;
  }
#pragma unroll
  for (int o = 32; o > 0; o >>= 1) {
    sum += __shfl_xor(sum, o);
    sq  += __shfl_xor(sq, o);
  }
  __shared__ float s_sum[4], s_sq[4];
  if (lane == 0) { s_sum[wave] = sum; s_sq[wave] = sq; }
  __syncthreads();
  const float ts = s_sum[0] + s_sum[1] + s_sum[2] + s_sum[3];
  const float tq = s_sq[0] + s_sq[1] + s_sq[2] + s_sq[3];
  const float mu  = ts * (1.f / HIDDEN);
  const float var = tq * (1.f / HIDDEN) - mu * mu;
  const float rs  = rsqrtf(var + EPS);
  short4* orow = (short4*)(out + (size_t)row * HIDDEN);
#pragma unroll
  for (int i = 0; i < 4; ++i) {
    float4 g = ((const float4*)gamma)[tid + i * 256];
    float4 b = ((const float4*)beta)[tid + i * 256];
    short4 o;
    o.x = f2bf((v[i].x - mu) * rs * g.x + b.x);
    o.y = f2bf((v[i].y - mu) * rs * g.y + b.y);
    o.z = f2bf((v[i].z - mu) * rs * g.z + b.z);
    o.w = f2bf((v[i].w - mu) * rs * g.w + b.w);
    orow[tid + i * 256] = o;
  }
}

// ---------- transpose + fp32->bf16: in [R,C] f32 -> out [C,R] bf16 ----------
__global__ __launch_bounds__(256) void transpose_bf16(
    const float* __restrict__ in, short* __restrict__ out, int R, int C) {
  __shared__ float tile[32][33];
  const int c0 = blockIdx.x * 32, r0 = blockIdx.y * 32;
  const int tx = threadIdx.x, ty = threadIdx.y;  // block (32,8)
#pragma unroll
  for (int i = 0; i < 32; i += 8)
    tile[ty + i][tx] = in[(size_t)(r0 + ty + i) * C + c0 + tx];
  __syncthreads();
#pragma unroll
  for (int i = 0; i < 32; i += 8)
    out[(size_t)(c0 + ty + i) * R + r0 + tx] = f2bf(tile[tx][ty + i]);
}

// =====================================================================
// bf16 GEMM, B^T layout — 256x256 tile, BK=64, 8-phase schedule
// (T1 XCD swizzle + T2 LDS XOR swizzle + T3/T4 counted vmcnt + T5 setprio)
// 512 threads = 8 waves (2M x 4N); per-wave output 128x64, fragments
// interleaved at 16-granularity.
// Quadrant order Q00->Q01->Q11->Q10 with BOTH B-halves persistent in regs
// so every LDS fragment is read exactly once: 24 ds_read_b128/K-tile/wave
// (was 32 with the A0 re-read) -> LDS pipe (~2304 cyc/CU/K-tile) drops
// below the MFMA pipe (~2483 cyc).
// LDS: 2 dbuf x (A:2 halves + B:2 halves) x [128][64] bf16 = 128 KiB.
// Swizzle: 16B-slot index ^= (row&7); global source pre-inverse-swizzled
// so global_load_lds dest stays linear (rule 21).
// =====================================================================
#define BM 256
#define BN 256
#define BK 64

__device__ __forceinline__ shortx8 frag_ld(const short* half, int rowbase,
                                           int kk, int lane) {
  const int row  = rowbase + (lane & 15);
  const int slot = (kk << 2) + (lane >> 4);         // 16B slot 0..7
  return *(const shortx8*)&half[row * BK + ((slot ^ (row & 7)) << 3)];
}

__device__ __forceinline__ void ds_a(shortx8 (&f)[4][2], const short* half,
                                     int rb, int lane) {
#pragma unroll
  for (int ii = 0; ii < 4; ++ii)
#pragma unroll
    for (int kk = 0; kk < 2; ++kk)
      f[ii][kk] = frag_ld(half, rb + ii * 32, kk, lane);
}

__device__ __forceinline__ void ds_b(shortx8 (&f)[2][2], const short* half,
                                     int rb, int lane) {
#pragma unroll
  for (int jj = 0; jj < 2; ++jj)
#pragma unroll
    for (int kk = 0; kk < 2; ++kk)
      f[jj][kk] = frag_ld(half, rb + jj * 64, kk, lane);
}

template <int IH, int JH>
__device__ __forceinline__ void mmq(floatx4 (&acc)[8][4],
                                    const shortx8 (&aF)[4][2],
                                    const shortx8 (&bF)[2][2]) {
#pragma unroll
  for (int ii = 0; ii < 4; ++ii)
#pragma unroll
    for (int jj = 0; jj < 2; ++jj) {
      floatx4 c = acc[IH * 4 + ii][JH * 2 + jj];
      c = __builtin_amdgcn_mfma_f32_16x16x32_bf16(aF[ii][0], bF[jj][0], c, 0, 0, 0);
      c = __builtin_amdgcn_mfma_f32_16x16x32_bf16(aF[ii][1], bF[jj][1], c, 0, 0, 0);
      acc[IH * 4 + ii][JH * 2 + jj] = c;
    }
}

// Stage one 128x64 half-tile: 16 chunks of 8 rows (1024 B each); wave issues
// 2 chunks (2 loads). Global column slot pre-XORed with row&7 so linear LDS
// dest + swizzled frag_ld form the same involution.
__device__ __forceinline__ void stage_half(const short* G, int K, int k0,
                                           short* lhalf, int wave, int lane) {
  const int r = lane >> 3;                        // row within chunk, 0..7
  const int c = ((lane & 7) ^ r) << 3;            // inverse-swizzled col
#pragma unroll
  for (int n = 0; n < 2; ++n) {
    const int chunk = wave * 2 + n;               // 0..15
    async_load16(G + (size_t)(chunk * 8 + r) * K + k0 + c,
                 lhalf + chunk * 512);            // 512 shorts = 1024 B
  }
}

#define BARRIER() asm volatile("s_barrier" ::: "memory")
#define VMCNT(N)  asm volatile("s_waitcnt vmcnt(" #N ")" ::: "memory")

template <bool GELU>
__global__ __launch_bounds__(512, 2) void gemm_bt(
    const short* __restrict__ A,   // [M,K] bf16
    const short* __restrict__ Bt,  // [N,K] bf16
    const float* __restrict__ bias,
    void* __restrict__ Cptr, int M, int N, int K) {
  __shared__ __align__(16) short lds[65536];  // 128 KiB
  short* sA = lds;                            // [2][2][8192]
  short* sB = lds + 32768;

  const int tid  = threadIdx.x;
  const int wave = tid >> 6, lane = tid & 63;
  const int wr16 = (wave >> 2) * 16;   // M sub-offset
  const int wc16 = (wave & 3) * 16;    // N sub-offset

  // T1: XCD-aware bijective swizzle (nwg % 8 == 0 for both GEMMs here)
  const int nwg  = gridDim.x * gridDim.y;
  const int orig = blockIdx.y * gridDim.x + blockIdx.x;
  const int swz  = (orig & 7) * (nwg >> 3) + (orig >> 3);
  const int m0 = (swz / gridDim.x) * BM;
  const int n0 = (swz % gridDim.x) * BN;

  const short* Ab    = A  + (size_t)m0 * K;
  const short* Bb    = Bt + (size_t)n0 * K;
  const short* Ab128 = Ab + (size_t)128 * K;
  const short* Bb128 = Bb + (size_t)128 * K;

  floatx4 acc[8][4] = {};
  shortx8 aF[4][2], bF0[2][2], bF1[2][2];

  const int NT = K / BK;

  // Prologue: stage tile 0 halves in consumption order A0,B0,B1,A1 (8 loads).
  // vmcnt(4) certifies A0,B0; B1,A1 (4 loads) stay in flight.
  stage_half(Ab,    K, 0, sA,        wave, lane);
  stage_half(Bb,    K, 0, sB,        wave, lane);
  stage_half(Bb128, K, 0, sB + 8192, wave, lane);
  stage_half(Ab128, K, 0, sA + 8192, wave, lane);
  VMCNT(4);
  BARRIER();

  // Steady-state ledger (per wave, 2 loads per stage), staging order per
  // tile: P1->A0', P2->B0', P3->B1', P4->A1'.
  //   end-P1: out={B1,A1,A0'}=6, need B1 for P2 -> vmcnt(4)
  //   end-P2: out={A1,A0',B0'}=6, need A1 for P3 -> vmcnt(4)
  //   end-P3: out=6, P4 reads nothing            -> no wait
  //   end-P4: out=8, need A0',B0' for next P1    -> vmcnt(4)
  for (int t = 0; t < NT - 1; ++t) {
    const int d = t & 1;
    const short* pA = sA + d * 16384;
    const short* pB = sB + d * 16384;
    short* qA = sA + (d ^ 1) * 16384;
    short* qB = sB + (d ^ 1) * 16384;
    const int kn = (t + 1) * BK;

    // P1: read A0,B0 ; stage A0' ; MFMA Q00 (A0 x B0)
    ds_a(aF, pA, wr16, lane);
    ds_b(bF0, pB, wc16, lane);
    stage_half(Ab, K, kn, qA, wave, lane);
    BARRIER();
    __builtin_amdgcn_sched_barrier(0);
    __builtin_amdgcn_s_setprio(1);
    mmq<0, 0>(acc, aF, bF0);
    __builtin_amdgcn_s_setprio(0);
    VMCNT(4);
    BARRIER();

    // P2: read B1 (keep A0 frags) ; stage B0' ; MFMA Q01 (A0 x B1)
    ds_b(bF1, pB + 8192, wc16, lane);
    stage_half(Bb, K, kn, qB, wave, lane);
    BARRIER();
    __builtin_amdgcn_sched_barrier(0);
    __builtin_amdgcn_s_setprio(1);
    mmq<0, 1>(acc, aF, bF1);
    __builtin_amdgcn_s_setprio(0);
    VMCNT(4);
    BARRIER();

    // P3: read A1 (keep B1 frags) ; stage B1' ; MFMA Q11 (A1 x B1)
    ds_a(aF, pA + 8192, wr16, lane);
    stage_half(Bb128, K, kn, qB + 8192, wave, lane);
    BARRIER();
    __builtin_amdgcn_sched_barrier(0);
    __builtin_amdgcn_s_setprio(1);
    mmq<1, 1>(acc, aF, bF1);
    __builtin_amdgcn_s_setprio(0);
    BARRIER();

    // P4: no ds reads (A1 in regs, B0 in regs) ; stage A1' ; MFMA Q10
    stage_half(Ab128, K, kn, qA + 8192, wave, lane);
    BARRIER();
    __builtin_amdgcn_sched_barrier(0);
    __builtin_amdgcn_s_setprio(1);
    mmq<1, 0>(acc, aF, bF0);
    __builtin_amdgcn_s_setprio(0);
    VMCNT(4);
    BARRIER();
  }

  // Last tile: no staging. Entry outstanding (per wave) = {B1,A1}.
  {
    const int d = (NT - 1) & 1;
    const short* pA = sA + d * 16384;
    const short* pB = sB + d * 16384;

    ds_a(aF, pA, wr16, lane);
    ds_b(bF0, pB, wc16, lane);
    BARRIER();
    __builtin_amdgcn_sched_barrier(0);
    __builtin_amdgcn_s_setprio(1);
    mmq<0, 0>(acc, aF, bF0);
    __builtin_amdgcn_s_setprio(0);
    VMCNT(2);            // certify B1
    BARRIER();

    ds_b(bF1, pB + 8192, wc16, lane);
    __builtin_amdgcn_s_setprio(1);
    mmq<0, 1>(acc, aF, bF1);
    __builtin_amdgcn_s_setprio(0);
    VMCNT(0);            // certify A1 (final drain — reads only after this)
    BARRIER();

    ds_a(aF, pA + 8192, wr16, lane);
    __builtin_amdgcn_s_setprio(1);
    mmq<1, 1>(acc, aF, bF1);
    mmq<1, 0>(acc, aF, bF0);
    __builtin_amdgcn_s_setprio(0);
  }

  // Epilogue: C/D layout col=lane&15, row=(lane>>4)*4+reg.
  const int quad = lane >> 4;
  const int cl   = lane & 15;
  float bv[4];
#pragma unroll
  for (int j = 0; j < 4; ++j) bv[j] = bias[n0 + wc16 + j * 64 + cl];
#pragma unroll
  for (int i = 0; i < 8; ++i) {
    const int gr = m0 + wr16 + i * 32 + quad * 4;
#pragma unroll
    for (int j = 0; j < 4; ++j) {
      const int gc = n0 + wc16 + j * 64 + cl;
#pragma unroll
      for (int r = 0; r < 4; ++r) {
        float v = acc[i][j][r] + bv[j];
        if constexpr (GELU) {
          v = 0.5f * v * (1.0f + erff(v * 0.70710678118654752f));
          ((short*)Cptr)[(size_t)(gr + r) * N + gc] = f2bf(v);
        } else {
          ((float*)Cptr)[(size_t)(gr + r) * N + gc] = v;
        }
      }
    }
  }
}

extern "C" void kernel_launch(void* const* d_in, const int* in_sizes, int n_in,
                              void* d_out, int out_size, void* d_ws, size_t ws_size,
                              hipStream_t stream) {
  const float* x     = (const float*)d_in[0];
  const float* gamma = (const float*)d_in[1];
  const float* beta  = (const float*)d_in[2];
  const float* fc1   = (const float*)d_in[3];  // [HIDDEN, FFN]
  const float* b1    = (const float*)d_in[4];  // [FFN]
  const float* fc2   = (const float*)d_in[5];  // [FFN, HIDDEN]
  const float* b2    = (const float*)d_in[6];  // [HIDDEN]
  float* out = (float*)d_out;

  // ws layout (peak 448 MiB):
  //   [0,128Mi)   fc1_bt [FFN,HIDDEN] bf16  -> later reused for fc2_bt
  //   [128,384Mi) h      [TOKENS,FFN] bf16
  //   [384,448Mi) ln     [TOKENS,HIDDEN] bf16
  char* ws = (char*)d_ws;
  const size_t MiB = 1024 * 1024;
  short* fc1_bt = (short*)(ws);
  short* h      = (short*)(ws + 128 * MiB);
  short* ln     = (short*)(ws + 384 * MiB);
  short* fc2_bt = (short*)(ws);  // overwrites fc1_bt after GEMM1 (stream-ordered)

  transpose_bf16<<<dim3(FFN / 32, HIDDEN / 32), dim3(32, 8), 0, stream>>>(
      fc1, fc1_bt, HIDDEN, FFN);
  ln_kernel<<<dim3(TOKENS), dim3(256), 0, stream>>>(x, gamma, beta, ln);
  gemm_bt<true><<<dim3(FFN / BN, TOKENS / BM), dim3(512), 0, stream>>>(
      ln, fc1_bt, b1, h, TOKENS, FFN, HIDDEN);
  transpose_bf16<<<dim3(HIDDEN / 32, FFN / 32), dim3(32, 8), 0, stream>>>(
      fc2, fc2_bt, FFN, HIDDEN);
  gemm_bt<false><<<dim3(HIDDEN / BN, TOKENS / BM), dim3(512), 0, stream>>>(
      h, fc2_bt, b2, out, TOKENS, HIDDEN, FFN);
}